// Round 6
// baseline (379.574 us; speedup 1.0000x reference)
//
#include <hip/hip_runtime.h>
#include <math.h>

// x:(4,16,256,128)f32  w_qkv:(128,384)  w_out:(128,128)  b_out:(128)  y:(4,16,256,128)f32
// Reshape map: J=pos>>7, d/e=(pos&127)*32+(c>>2), a=c&3.  Per (b,a) pair:
// flash attn seq=4096 dim=32, Q=(10*log2e)*l2norm4(k), K=V=M(v), M[e][J]=v.
// Log2-domain softmax; exact per-row max from phase-1 bf16 QK sweep,
// subtracted for free via MFMA C-operand init in phase 2.
// ws (24MB): Qhi|Qlo [pair][d][J] bf16, Mhi|Mlo [pair][e][J] bf16,
//            Mpv [pair][J][e~] bf16 (r2/r5-exact layout), outb bf16.

#define SEQ 4096
#define PAIR_ELEMS (SEQ * 32)

typedef __attribute__((ext_vector_type(8))) short bf16x8;
typedef __attribute__((ext_vector_type(4))) float f32x4;

static __device__ __forceinline__ unsigned short f2bf(float x) {
    unsigned u = __float_as_uint(x);
    u += 0x7fffu + ((u >> 16) & 1u);
    return (unsigned short)(u >> 16);
}
static __device__ __forceinline__ float bf2f(unsigned short h) {
    return __uint_as_float(((unsigned)h) << 16);
}

// ---------------------------------------------------------------------------
// Kernel 1: k/v GEMM + in-thread l2norm + bf16 hi/lo split.
// Thread owns 4 consecutive channels x 8 J-rows (acc[8][4]): 4x fewer LDS
// reads than r5, float4 w-loads, zero-shfl l2norm. Store layouts byte-
// identical to the r5 passing kernel; Mpv scatter loop verbatim.
// ---------------------------------------------------------------------------
__global__ __launch_bounds__(256) void kv_kernel(const float* __restrict__ x,
                                                 const float* __restrict__ wqkv,
                                                 unsigned short* __restrict__ Qhi,
                                                 unsigned short* __restrict__ Qlo,
                                                 unsigned short* __restrict__ Mhi,
                                                 unsigned short* __restrict__ Mlo,
                                                 unsigned short* __restrict__ Mpv) {
    __shared__ __align__(16) float xs[32][128];          // 16 KB
    __shared__ __align__(8) unsigned short vstage[32][128];  // 8 KB

    const int b    = blockIdx.x >> 7;
    const int p7   = blockIdx.x & 127;
    const int t    = threadIdx.x;
    const int half = t >> 7;          // waves 0-1: k, waves 2-3: v
    const int u    = t & 127;
    const int q    = u & 31;          // channel group (cg) 0..31
    const int rg   = u >> 5;          // J-block: rows 8rg..8rg+7
    const int woff = 128 + (half << 7) + (q << 2);

    // stage x rows (coalesced float4)
    {
        const float* xb = x + ((size_t)(b * SEQ + p7)) * 128;
#pragma unroll
        for (int uu = 0; uu < 4; ++uu) {
            int idx = t + (uu << 8);               // 0..1023
            int j   = idx >> 5;
            int c4  = idx & 31;
            *(float4*)&xs[j][c4 * 4] =
                *(const float4*)(xb + (size_t)j * (128 * 128) + c4 * 4);
        }
    }
    __syncthreads();

    float acc[8][4];
#pragma unroll
    for (int jr = 0; jr < 8; ++jr)
#pragma unroll
        for (int a = 0; a < 4; ++a) acc[jr][a] = 0.f;

    for (int i4 = 0; i4 < 128; i4 += 4) {
        float4 wv[4];
#pragma unroll
        for (int i = 0; i < 4; ++i)
            wv[i] = *(const float4*)(wqkv + (size_t)(i4 + i) * 384 + woff);
#pragma unroll
        for (int jr = 0; jr < 8; ++jr) {
            float4 xv = *(const float4*)&xs[8 * rg + jr][i4];
            acc[jr][0] = fmaf(xv.x, wv[0].x, acc[jr][0]);
            acc[jr][1] = fmaf(xv.x, wv[0].y, acc[jr][1]);
            acc[jr][2] = fmaf(xv.x, wv[0].z, acc[jr][2]);
            acc[jr][3] = fmaf(xv.x, wv[0].w, acc[jr][3]);
            acc[jr][0] = fmaf(xv.y, wv[1].x, acc[jr][0]);
            acc[jr][1] = fmaf(xv.y, wv[1].y, acc[jr][1]);
            acc[jr][2] = fmaf(xv.y, wv[1].z, acc[jr][2]);
            acc[jr][3] = fmaf(xv.y, wv[1].w, acc[jr][3]);
            acc[jr][0] = fmaf(xv.z, wv[2].x, acc[jr][0]);
            acc[jr][1] = fmaf(xv.z, wv[2].y, acc[jr][1]);
            acc[jr][2] = fmaf(xv.z, wv[2].z, acc[jr][2]);
            acc[jr][3] = fmaf(xv.z, wv[2].w, acc[jr][3]);
            acc[jr][0] = fmaf(xv.w, wv[3].x, acc[jr][0]);
            acc[jr][1] = fmaf(xv.w, wv[3].y, acc[jr][1]);
            acc[jr][2] = fmaf(xv.w, wv[3].z, acc[jr][2]);
            acc[jr][3] = fmaf(xv.w, wv[3].w, acc[jr][3]);
        }
    }

    const int pairbase = b << 2;
    const int de = (p7 << 5) + q;

    if (half == 0) {
        // Q = (10*log2e) * l2norm over the 4 in-thread channels — no shfl
        float qn[8][4];
#pragma unroll
        for (int jr = 0; jr < 8; ++jr) {
            float s = acc[jr][0] * acc[jr][0] + acc[jr][1] * acc[jr][1]
                    + acc[jr][2] * acc[jr][2] + acc[jr][3] * acc[jr][3];
            float inv = 14.426950408889634f / fmaxf(sqrtf(s), 1e-12f);
#pragma unroll
            for (int a = 0; a < 4; ++a) qn[jr][a] = acc[jr][a] * inv;
        }
#pragma unroll
        for (int a = 0; a < 4; ++a) {
            unsigned hi[4], lo[4];
#pragma unroll
            for (int j2 = 0; j2 < 4; ++j2) {
                float v0 = qn[2 * j2][a], v1 = qn[2 * j2 + 1][a];
                unsigned short h0 = f2bf(v0), h1 = f2bf(v1);
                hi[j2] = (unsigned)h0 | ((unsigned)h1 << 16);
                lo[j2] = (unsigned)f2bf(v0 - bf2f(h0))
                       | ((unsigned)f2bf(v1 - bf2f(h1)) << 16);
            }
            size_t off = (size_t)(pairbase + a) * PAIR_ELEMS + (size_t)de * 32 + 8 * rg;
            *(uint4*)(Qhi + off) = make_uint4(hi[0], hi[1], hi[2], hi[3]);
            *(uint4*)(Qlo + off) = make_uint4(lo[0], lo[1], lo[2], lo[3]);
        }
    } else {
#pragma unroll
        for (int a = 0; a < 4; ++a) {
            unsigned hi[4], lo[4];
#pragma unroll
            for (int j2 = 0; j2 < 4; ++j2) {
                float v0 = acc[2 * j2][a], v1 = acc[2 * j2 + 1][a];
                unsigned short h0 = f2bf(v0), h1 = f2bf(v1);
                hi[j2] = (unsigned)h0 | ((unsigned)h1 << 16);
                lo[j2] = (unsigned)f2bf(v0 - bf2f(h0))
                       | ((unsigned)f2bf(v1 - bf2f(h1)) << 16);
            }
            size_t off = (size_t)(pairbase + a) * PAIR_ELEMS + (size_t)de * 32 + 8 * rg;
            *(uint4*)(Mhi + off) = make_uint4(hi[0], hi[1], hi[2], hi[3]);
            *(uint4*)(Mlo + off) = make_uint4(lo[0], lo[1], lo[2], lo[3]);
        }
        // vstage[J][cv]: cv = 4q+a, bf16 hi values (8-B packed writes)
#pragma unroll
        for (int jr = 0; jr < 8; ++jr) {
            unsigned short h0 = f2bf(acc[jr][0]);
            unsigned short h1 = f2bf(acc[jr][1]);
            unsigned short h2 = f2bf(acc[jr][2]);
            unsigned short h3 = f2bf(acc[jr][3]);
            *(uint2*)&vstage[8 * rg + jr][4 * q] =
                make_uint2((unsigned)h0 | ((unsigned)h1 << 16),
                           (unsigned)h2 | ((unsigned)h3 << 16));
        }
    }
    __syncthreads();

    // Mpv[pair][J][e~] scatter — verbatim from the r2/r5 passing kernels.
    unsigned* mpv32 = (unsigned*)Mpv;
#pragma unroll
    for (int uu = 0; uu < 8; ++uu) {
        int task = t + (uu << 8);                  // 2048 tasks
        int r  = task & 15;
        int jj = (task >> 4) & 31;
        int aa = task >> 9;
        unsigned lo = vstage[jj][(r << 2) + aa];
        unsigned hi = vstage[jj][(r << 2) + aa + 64];
        int pr = (b << 2) + aa;
        size_t dst = (size_t)pr * (PAIR_ELEMS / 2) + (size_t)jj * (SEQ / 2)
                   + ((size_t)(p7 >> 1) << 5) + (r << 1) + (p7 & 1);
        mpv32[dst] = lo | (hi << 16);
    }
}

// ---------------------------------------------------------------------------
// Kernel 2: MFMA flash attention. 1024 blocks x 4 waves x 16 d-rows
// (2x occupancy vs r5). Same two-phase max-free softmax; all 12 B-operand
// loads issued at iteration top so bv's L2 latency hides under QK+softmax.
// ---------------------------------------------------------------------------
__global__ __launch_bounds__(256, 4) void attn_kernel(const unsigned short* __restrict__ Qhi,
                                                      const unsigned short* __restrict__ Qlo,
                                                      const unsigned short* __restrict__ Mhi,
                                                      const unsigned short* __restrict__ Mlo,
                                                      const unsigned short* __restrict__ Mpv,
                                                      unsigned short* __restrict__ outb) {
    __shared__ __align__(16) unsigned short Plds[4][16][72];  // 9 KB

    const int bid  = blockIdx.x;                       // 1024
    const int pair = ((bid & 7) << 1) | (bid >> 9);    // pair pinned to XCD
    const int dblk = (bid >> 3) & 63;
    const int t    = threadIdx.x;
    const int wid  = t >> 6;
    const int lane = t & 63;
    const int col  = lane & 15;
    const int g    = lane >> 4;
    const int d0   = dblk * 64 + wid * 16;

    const size_t pb = (size_t)pair * PAIR_ELEMS;

    bf16x8 ah = *(const bf16x8*)(Qhi + pb + (size_t)(d0 + col) * 32 + g * 8);
    bf16x8 al = *(const bf16x8*)(Qlo + pb + (size_t)(d0 + col) * 32 + g * 8);

    const unsigned short* mh = Mhi + pb;
    const unsigned short* ml = Mlo + pb;
    const unsigned short* mp = Mpv + pb;          // [32 J][4096 e~]
    const f32x4 z = {0.f, 0.f, 0.f, 0.f};

    // ---- phase 1: exact row max of bf16 QK (no cross-lane in loop)
    float rmax[4] = {-3e38f, -3e38f, -3e38f, -3e38f};
    for (int e0 = 0; e0 < SEQ; e0 += 64) {
        bf16x8 bh[4];
#pragma unroll
        for (int cc = 0; cc < 4; ++cc)
            bh[cc] = *(const bf16x8*)(mh + (size_t)(e0 + 16 * cc + col) * 32 + g * 8);
#pragma unroll
        for (int cc = 0; cc < 4; ++cc) {
            f32x4 sv = __builtin_amdgcn_mfma_f32_16x16x32_bf16(ah, bh[cc], z, 0, 0, 0);
#pragma unroll
            for (int r = 0; r < 4; ++r) rmax[r] = fmaxf(rmax[r], sv[r]);
        }
    }
#pragma unroll
    for (int r = 0; r < 4; ++r) {
        float m = rmax[r];
        m = fmaxf(m, __shfl_xor(m, 1));
        m = fmaxf(m, __shfl_xor(m, 2));
        m = fmaxf(m, __shfl_xor(m, 4));
        m = fmaxf(m, __shfl_xor(m, 8));
        rmax[r] = m;
    }
    const f32x4 minit = {-rmax[0], -rmax[1], -rmax[2], -rmax[3]};

    f32x4 O[2];
    O[0] = (f32x4){0.f, 0.f, 0.f, 0.f};
    O[1] = (f32x4){0.f, 0.f, 0.f, 0.f};
    float lsum[4] = {0.f, 0.f, 0.f, 0.f};

    // ---- phase 2: main flash loop
    for (int e0 = 0; e0 < SEQ; e0 += 64) {
        bf16x8 bh[4], bl[4], bv[4];
#pragma unroll
        for (int cc = 0; cc < 4; ++cc) {
            size_t ro = (size_t)(e0 + 16 * cc + col) * 32 + g * 8;
            bh[cc] = *(const bf16x8*)(mh + ro);
            bl[cc] = *(const bf16x8*)(ml + ro);
        }
#pragma unroll
        for (int h = 0; h < 2; ++h)
#pragma unroll
            for (int nh = 0; nh < 2; ++nh)
                bv[2 * h + nh] = *(const bf16x8*)(mp + (size_t)(16 * nh + col) * SEQ
                                                  + e0 + 32 * h + g * 8);

        f32x4 S[4];
#pragma unroll
        for (int cc = 0; cc < 4; ++cc) {
            f32x4 tac = __builtin_amdgcn_mfma_f32_16x16x32_bf16(ah, bl[cc], minit, 0, 0, 0);
            tac = __builtin_amdgcn_mfma_f32_16x16x32_bf16(al, bh[cc], tac, 0, 0, 0);
            S[cc] = __builtin_amdgcn_mfma_f32_16x16x32_bf16(ah, bh[cc], tac, 0, 0, 0);
        }
        // P = exp2(S), per-lane l partials, P -> LDS (bf16)
#pragma unroll
        for (int r = 0; r < 4; ++r) {
            float p0 = __builtin_amdgcn_exp2f(S[0][r]);
            float p1 = __builtin_amdgcn_exp2f(S[1][r]);
            float p2 = __builtin_amdgcn_exp2f(S[2][r]);
            float p3 = __builtin_amdgcn_exp2f(S[3][r]);
            lsum[r] += (p0 + p1) + (p2 + p3);
            unsigned w0 = (unsigned)f2bf(p0) | ((unsigned)f2bf(p1) << 16);
            unsigned w1 = (unsigned)f2bf(p2) | ((unsigned)f2bf(p3) << 16);
            unsigned* dst = (unsigned*)&Plds[wid][4 * g + r][col * 4];
            dst[0] = w0;
            dst[1] = w1;
        }
        asm volatile("s_waitcnt lgkmcnt(0)" ::: "memory");
        __builtin_amdgcn_sched_barrier(0);
        // O += P * M  (bv already in registers)
#pragma unroll
        for (int h = 0; h < 2; ++h) {
            bf16x8 pa = *(const bf16x8*)&Plds[wid][col][32 * h + g * 8];
            O[0] = __builtin_amdgcn_mfma_f32_16x16x32_bf16(pa, bv[2 * h + 0], O[0], 0, 0, 0);
            O[1] = __builtin_amdgcn_mfma_f32_16x16x32_bf16(pa, bv[2 * h + 1], O[1], 0, 0, 0);
        }
        // keep program order: this iter's Plds reads before next iter's writes
        asm volatile("" ::: "memory");
    }

    // ---- final l reduce across the 16 col-lanes
#pragma unroll
    for (int r = 0; r < 4; ++r) {
        float l = lsum[r];
        l += __shfl_xor(l, 1);
        l += __shfl_xor(l, 2);
        l += __shfl_xor(l, 4);
        l += __shfl_xor(l, 8);
        lsum[r] = l;
    }

    // ---- epilogue: outb[b][d][n2*4+a] = O/l (bf16)
    const int bb = pair >> 2;
    const int aa = pair & 3;
#pragma unroll
    for (int r = 0; r < 4; ++r) {
        int d = d0 + 4 * g + r;
        float inv = 1.0f / lsum[r];
#pragma unroll
        for (int nh = 0; nh < 2; ++nh) {
            int n2 = 16 * nh + col;
            outb[((size_t)(bb * SEQ + d)) * 128 + n2 * 4 + aa] = f2bf(O[nh][r] * inv);
        }
    }
}

// ---------------------------------------------------------------------------
// Kernel 3: y = opre(bf16) @ w_out + b_out  (fp32 vector GEMM) — r5-exact
// ---------------------------------------------------------------------------
__global__ __launch_bounds__(256) void out_kernel(const unsigned short* __restrict__ opre,
                                                  const float* __restrict__ wout,
                                                  const float* __restrict__ bout,
                                                  float* __restrict__ y) {
    __shared__ __align__(16) float xs[8][128];
    const int r0 = blockIdx.x * 8;
    const int t  = threadIdx.x;
    {
        const unsigned* src = (const unsigned*)(opre + (size_t)r0 * 128);
        unsigned v0 = src[t * 2], v1 = src[t * 2 + 1];
        float* dst = &xs[0][0] + t * 4;
        dst[0] = bf2f((unsigned short)(v0 & 0xffff));
        dst[1] = bf2f((unsigned short)(v0 >> 16));
        dst[2] = bf2f((unsigned short)(v1 & 0xffff));
        dst[3] = bf2f((unsigned short)(v1 >> 16));
    }
    __syncthreads();

    const int c  = t & 127;
    const int rh = (t >> 7) * 4;
    float acc[4] = {0.f, 0.f, 0.f, 0.f};

    for (int i = 0; i < 128; i += 4) {
        float w0 = wout[(i + 0) * 128 + c];
        float w1 = wout[(i + 1) * 128 + c];
        float w2 = wout[(i + 2) * 128 + c];
        float w3 = wout[(i + 3) * 128 + c];
#pragma unroll
        for (int p = 0; p < 4; ++p) {
            float4 xp = *(const float4*)&xs[rh + p][i];
            acc[p] = fmaf(xp.x, w0, acc[p]);
            acc[p] = fmaf(xp.y, w1, acc[p]);
            acc[p] = fmaf(xp.z, w2, acc[p]);
            acc[p] = fmaf(xp.w, w3, acc[p]);
        }
    }
    float bb = bout[c];
#pragma unroll
    for (int p = 0; p < 4; ++p) {
        y[((size_t)(r0 + rh + p)) * 128 + c] = acc[p] + bb;
    }
}

// ---------------------------------------------------------------------------
extern "C" void kernel_launch(void* const* d_in, const int* in_sizes, int n_in,
                              void* d_out, int out_size, void* d_ws, size_t ws_size,
                              hipStream_t stream) {
    const float* x    = (const float*)d_in[0];
    const float* wqkv = (const float*)d_in[1];
    const float* wout = (const float*)d_in[2];
    const float* bout = (const float*)d_in[3];
    float* y = (float*)d_out;

    unsigned short* Qhi = (unsigned short*)d_ws;
    unsigned short* Qlo = Qhi + (size_t)16 * PAIR_ELEMS;
    unsigned short* Mhi = Qlo + (size_t)16 * PAIR_ELEMS;
    unsigned short* Mlo = Mhi + (size_t)16 * PAIR_ELEMS;
    unsigned short* Mpv = Mlo + (size_t)16 * PAIR_ELEMS;
    unsigned short* outb = Mpv + (size_t)16 * PAIR_ELEMS;

    kv_kernel<<<512, 256, 0, stream>>>(x, wqkv, Qhi, Qlo, Mhi, Mlo, Mpv);
    attn_kernel<<<1024, 256, 0, stream>>>(Qhi, Qlo, Mhi, Mlo, Mpv, outb);
    out_kernel<<<2048, 256, 0, stream>>>(outb, wout, bout, y);
}

// Round 7
// 259.630 us; speedup vs baseline: 1.4620x; 1.4620x over previous
//
#include <hip/hip_runtime.h>
#include <math.h>

// x:(4,16,256,128)f32  w_qkv:(128,384)  w_out:(128,128)  b_out:(128)  y:(4,16,256,128)f32
// Reshape map: J=pos>>7, d/e=(pos&127)*32+(c>>2), a=c&3.  Per (b,a) pair:
// flash attn seq=4096 dim=32, Q=(10*log2e)*l2norm4(k), K=V=M(v), M[e][J]=v.
// Log2-domain softmax; exact per-row max from phase-1 bf16 QK sweep,
// subtracted for free via MFMA C-operand init in phase 2.
// r7: r5 geometry (512 blocks x 4 waves x 32 rows) + depth-1 register
// prefetch software pipeline in both phases (and in kv's w-loads) to break
// the ~4000-cycle serial per-iteration load-latency chain found in r5/r6.
// ws (24MB): Qhi|Qlo [pair][d][J] bf16, Mhi|Mlo [pair][e][J] bf16,
//            Mpv [pair][J][e~] bf16 (r2/r5-exact layout), outb bf16.

#define SEQ 4096
#define PAIR_ELEMS (SEQ * 32)

typedef __attribute__((ext_vector_type(8))) short bf16x8;
typedef __attribute__((ext_vector_type(4))) float f32x4;

static __device__ __forceinline__ unsigned short f2bf(float x) {
    unsigned u = __float_as_uint(x);
    u += 0x7fffu + ((u >> 16) & 1u);
    return (unsigned short)(u >> 16);
}
static __device__ __forceinline__ float bf2f(unsigned short h) {
    return __uint_as_float(((unsigned)h) << 16);
}

// ---------------------------------------------------------------------------
// Kernel 1: k/v GEMM + in-thread l2norm + bf16 hi/lo split (r6 structure,
// which improved kv ~100->~55us) + depth-1 prefetch of the w-tiles.
// Store layouts byte-identical to r5/r6 passing kernels.
// ---------------------------------------------------------------------------
__global__ __launch_bounds__(256) void kv_kernel(const float* __restrict__ x,
                                                 const float* __restrict__ wqkv,
                                                 unsigned short* __restrict__ Qhi,
                                                 unsigned short* __restrict__ Qlo,
                                                 unsigned short* __restrict__ Mhi,
                                                 unsigned short* __restrict__ Mlo,
                                                 unsigned short* __restrict__ Mpv) {
    __shared__ __align__(16) float xs[32][128];          // 16 KB
    __shared__ __align__(8) unsigned short vstage[32][128];  // 8 KB

    const int b    = blockIdx.x >> 7;
    const int p7   = blockIdx.x & 127;
    const int t    = threadIdx.x;
    const int half = t >> 7;          // waves 0-1: k, waves 2-3: v
    const int u    = t & 127;
    const int q    = u & 31;          // channel group (cg) 0..31
    const int rg   = u >> 5;          // J-block: rows 8rg..8rg+7
    const int woff = 128 + (half << 7) + (q << 2);

    // stage x rows (coalesced float4)
    {
        const float* xb = x + ((size_t)(b * SEQ + p7)) * 128;
#pragma unroll
        for (int uu = 0; uu < 4; ++uu) {
            int idx = t + (uu << 8);               // 0..1023
            int j   = idx >> 5;
            int c4  = idx & 31;
            *(float4*)&xs[j][c4 * 4] =
                *(const float4*)(xb + (size_t)j * (128 * 128) + c4 * 4);
        }
    }
    __syncthreads();

    float acc[8][4];
#pragma unroll
    for (int jr = 0; jr < 8; ++jr)
#pragma unroll
        for (int a = 0; a < 4; ++a) acc[jr][a] = 0.f;

    // depth-1 prefetch pipeline on the w-tiles (static A/B register sets)
    float4 wA[4], wB[4];
#pragma unroll
    for (int i = 0; i < 4; ++i)
        wA[i] = *(const float4*)(wqkv + (size_t)i * 384 + woff);

    auto gstep = [&](float4 (&wcur)[4], float4 (&wnxt)[4], int i4) {
        const int i4n = (i4 + 4) & 127;            // wraps harmlessly on last
#pragma unroll
        for (int i = 0; i < 4; ++i)
            wnxt[i] = *(const float4*)(wqkv + (size_t)(i4n + i) * 384 + woff);
#pragma unroll
        for (int jr = 0; jr < 8; ++jr) {
            float4 xv = *(const float4*)&xs[8 * rg + jr][i4];
            acc[jr][0] = fmaf(xv.x, wcur[0].x, acc[jr][0]);
            acc[jr][1] = fmaf(xv.x, wcur[0].y, acc[jr][1]);
            acc[jr][2] = fmaf(xv.x, wcur[0].z, acc[jr][2]);
            acc[jr][3] = fmaf(xv.x, wcur[0].w, acc[jr][3]);
            acc[jr][0] = fmaf(xv.y, wcur[1].x, acc[jr][0]);
            acc[jr][1] = fmaf(xv.y, wcur[1].y, acc[jr][1]);
            acc[jr][2] = fmaf(xv.y, wcur[1].z, acc[jr][2]);
            acc[jr][3] = fmaf(xv.y, wcur[1].w, acc[jr][3]);
            acc[jr][0] = fmaf(xv.z, wcur[2].x, acc[jr][0]);
            acc[jr][1] = fmaf(xv.z, wcur[2].y, acc[jr][1]);
            acc[jr][2] = fmaf(xv.z, wcur[2].z, acc[jr][2]);
            acc[jr][3] = fmaf(xv.z, wcur[2].w, acc[jr][3]);
            acc[jr][0] = fmaf(xv.w, wcur[3].x, acc[jr][0]);
            acc[jr][1] = fmaf(xv.w, wcur[3].y, acc[jr][1]);
            acc[jr][2] = fmaf(xv.w, wcur[3].z, acc[jr][2]);
            acc[jr][3] = fmaf(xv.w, wcur[3].w, acc[jr][3]);
        }
    };
    for (int i4 = 0; i4 < 128; i4 += 8) {
        gstep(wA, wB, i4);
        gstep(wB, wA, i4 + 4);
    }

    const int pairbase = b << 2;
    const int de = (p7 << 5) + q;

    if (half == 0) {
        // Q = (10*log2e) * l2norm over the 4 in-thread channels — no shfl
        float qn[8][4];
#pragma unroll
        for (int jr = 0; jr < 8; ++jr) {
            float s = acc[jr][0] * acc[jr][0] + acc[jr][1] * acc[jr][1]
                    + acc[jr][2] * acc[jr][2] + acc[jr][3] * acc[jr][3];
            float inv = 14.426950408889634f / fmaxf(sqrtf(s), 1e-12f);
#pragma unroll
            for (int a = 0; a < 4; ++a) qn[jr][a] = acc[jr][a] * inv;
        }
#pragma unroll
        for (int a = 0; a < 4; ++a) {
            unsigned hi[4], lo[4];
#pragma unroll
            for (int j2 = 0; j2 < 4; ++j2) {
                float v0 = qn[2 * j2][a], v1 = qn[2 * j2 + 1][a];
                unsigned short h0 = f2bf(v0), h1 = f2bf(v1);
                hi[j2] = (unsigned)h0 | ((unsigned)h1 << 16);
                lo[j2] = (unsigned)f2bf(v0 - bf2f(h0))
                       | ((unsigned)f2bf(v1 - bf2f(h1)) << 16);
            }
            size_t off = (size_t)(pairbase + a) * PAIR_ELEMS + (size_t)de * 32 + 8 * rg;
            *(uint4*)(Qhi + off) = make_uint4(hi[0], hi[1], hi[2], hi[3]);
            *(uint4*)(Qlo + off) = make_uint4(lo[0], lo[1], lo[2], lo[3]);
        }
    } else {
#pragma unroll
        for (int a = 0; a < 4; ++a) {
            unsigned hi[4], lo[4];
#pragma unroll
            for (int j2 = 0; j2 < 4; ++j2) {
                float v0 = acc[2 * j2][a], v1 = acc[2 * j2 + 1][a];
                unsigned short h0 = f2bf(v0), h1 = f2bf(v1);
                hi[j2] = (unsigned)h0 | ((unsigned)h1 << 16);
                lo[j2] = (unsigned)f2bf(v0 - bf2f(h0))
                       | ((unsigned)f2bf(v1 - bf2f(h1)) << 16);
            }
            size_t off = (size_t)(pairbase + a) * PAIR_ELEMS + (size_t)de * 32 + 8 * rg;
            *(uint4*)(Mhi + off) = make_uint4(hi[0], hi[1], hi[2], hi[3]);
            *(uint4*)(Mlo + off) = make_uint4(lo[0], lo[1], lo[2], lo[3]);
        }
        // vstage[J][cv]: cv = 4q+a, bf16 hi values (8-B packed writes)
#pragma unroll
        for (int jr = 0; jr < 8; ++jr) {
            unsigned short h0 = f2bf(acc[jr][0]);
            unsigned short h1 = f2bf(acc[jr][1]);
            unsigned short h2 = f2bf(acc[jr][2]);
            unsigned short h3 = f2bf(acc[jr][3]);
            *(uint2*)&vstage[8 * rg + jr][4 * q] =
                make_uint2((unsigned)h0 | ((unsigned)h1 << 16),
                           (unsigned)h2 | ((unsigned)h3 << 16));
        }
    }
    __syncthreads();

    // Mpv[pair][J][e~] scatter — verbatim from the r2/r5/r6 passing kernels.
    unsigned* mpv32 = (unsigned*)Mpv;
#pragma unroll
    for (int uu = 0; uu < 8; ++uu) {
        int task = t + (uu << 8);                  // 2048 tasks
        int r  = task & 15;
        int jj = (task >> 4) & 31;
        int aa = task >> 9;
        unsigned lo = vstage[jj][(r << 2) + aa];
        unsigned hi = vstage[jj][(r << 2) + aa + 64];
        int pr = (b << 2) + aa;
        size_t dst = (size_t)pr * (PAIR_ELEMS / 2) + (size_t)jj * (SEQ / 2)
                   + ((size_t)(p7 >> 1) << 5) + (r << 1) + (p7 & 1);
        mpv32[dst] = lo | (hi << 16);
    }
}

// ---------------------------------------------------------------------------
// Kernel 2: MFMA flash attention — r5 geometry (512 blocks x 4 waves x 32
// d-rows, Plds[4][32][72]) + depth-1 register-prefetch pipeline: tile i+1's
// 12 B-operand loads issue at the top of iteration i, hiding the ~1000-cyc
// load latency under QK/softmax/PV of tile i. Numerics identical to r5.
// ---------------------------------------------------------------------------
__global__ __launch_bounds__(256, 2) void attn_kernel(const unsigned short* __restrict__ Qhi,
                                                      const unsigned short* __restrict__ Qlo,
                                                      const unsigned short* __restrict__ Mhi,
                                                      const unsigned short* __restrict__ Mlo,
                                                      const unsigned short* __restrict__ Mpv,
                                                      unsigned short* __restrict__ outb) {
    __shared__ __align__(16) unsigned short Plds[4][32][72];  // 18 KB

    const int bid  = blockIdx.x;                 // 512
    const int pair = ((bid & 7) << 1) + (bid >> 8);   // 2 pairs per XCD slot
    const int dblk = (bid & 255) >> 3;                // 0..31
    const int t    = threadIdx.x;
    const int wid  = t >> 6;
    const int lane = t & 63;
    const int col  = lane & 15;
    const int g    = lane >> 4;
    const int d0   = dblk * 128 + wid * 32;

    const size_t pb = (size_t)pair * PAIR_ELEMS;

    bf16x8 ah[2], al[2];
#pragma unroll
    for (int s = 0; s < 2; ++s) {
        size_t o = pb + (size_t)(d0 + 16 * s + col) * 32 + g * 8;
        ah[s] = *(const bf16x8*)(Qhi + o);
        al[s] = *(const bf16x8*)(Qlo + o);
    }

    const unsigned short* mh = Mhi + pb;
    const unsigned short* ml = Mlo + pb;
    const unsigned short* mp = Mpv + pb;          // [32 J][4096 e~]
    const f32x4 z = {0.f, 0.f, 0.f, 0.f};

    // ---- phase 1: exact row max of bf16 QK, depth-1 prefetch
    float rmax[2][4];
#pragma unroll
    for (int s = 0; s < 2; ++s)
#pragma unroll
        for (int r = 0; r < 4; ++r) rmax[s][r] = -3e38f;

    {
        bf16x8 pA[4], pB[4];
#pragma unroll
        for (int cc = 0; cc < 4; ++cc)
            pA[cc] = *(const bf16x8*)(mh + (size_t)(16 * cc + col) * 32 + g * 8);

        auto sweep = [&](bf16x8 (&cur)[4], bf16x8 (&nxt)[4], int e0) {
            const int en = (e0 + 64) & (SEQ - 1);  // wraps harmlessly on last
#pragma unroll
            for (int cc = 0; cc < 4; ++cc)
                nxt[cc] = *(const bf16x8*)(mh + (size_t)(en + 16 * cc + col) * 32 + g * 8);
#pragma unroll
            for (int cc = 0; cc < 4; ++cc) {
#pragma unroll
                for (int s = 0; s < 2; ++s) {
                    f32x4 sv = __builtin_amdgcn_mfma_f32_16x16x32_bf16(ah[s], cur[cc], z, 0, 0, 0);
#pragma unroll
                    for (int r = 0; r < 4; ++r) rmax[s][r] = fmaxf(rmax[s][r], sv[r]);
                }
            }
        };
        for (int e0 = 0; e0 < SEQ; e0 += 128) {
            sweep(pA, pB, e0);
            sweep(pB, pA, e0 + 64);
        }
    }
#pragma unroll
    for (int s = 0; s < 2; ++s)
#pragma unroll
        for (int r = 0; r < 4; ++r) {
            float m = rmax[s][r];
            m = fmaxf(m, __shfl_xor(m, 1));
            m = fmaxf(m, __shfl_xor(m, 2));
            m = fmaxf(m, __shfl_xor(m, 4));
            m = fmaxf(m, __shfl_xor(m, 8));
            rmax[s][r] = m;
        }
    f32x4 minit[2];
#pragma unroll
    for (int s = 0; s < 2; ++s)
        minit[s] = (f32x4){-rmax[s][0], -rmax[s][1], -rmax[s][2], -rmax[s][3]};

    f32x4 O[2][2];
    float lsum[2][4];
#pragma unroll
    for (int s = 0; s < 2; ++s) {
#pragma unroll
        for (int r = 0; r < 4; ++r) lsum[s][r] = 0.f;
#pragma unroll
        for (int nh = 0; nh < 2; ++nh) O[s][nh] = (f32x4){0.f, 0.f, 0.f, 0.f};
    }

    // ---- phase 2: main flash loop, depth-1 prefetch of all 12 B-operands.
    // tile reg layout: [0..3]=Mhi(cc), [4..7]=Mlo(cc), [8..11]=Mpv(2h+nh)
    {
        bf16x8 tA[12], tB[12];
#pragma unroll
        for (int cc = 0; cc < 4; ++cc) {
            size_t ro = (size_t)(16 * cc + col) * 32 + g * 8;
            tA[cc]     = *(const bf16x8*)(mh + ro);
            tA[4 + cc] = *(const bf16x8*)(ml + ro);
        }
#pragma unroll
        for (int h = 0; h < 2; ++h)
#pragma unroll
            for (int nh = 0; nh < 2; ++nh)
                tA[8 + 2 * h + nh] =
                    *(const bf16x8*)(mp + (size_t)(16 * nh + col) * SEQ + 32 * h + g * 8);

        auto flash = [&](bf16x8 (&cur)[12], bf16x8 (&nxt)[12], int e0) {
            const int en = (e0 + 64) & (SEQ - 1);  // wraps harmlessly on last
            // prefetch next tile (issued before any use of cur)
#pragma unroll
            for (int cc = 0; cc < 4; ++cc) {
                size_t ro = (size_t)(en + 16 * cc + col) * 32 + g * 8;
                nxt[cc]     = *(const bf16x8*)(mh + ro);
                nxt[4 + cc] = *(const bf16x8*)(ml + ro);
            }
#pragma unroll
            for (int h = 0; h < 2; ++h)
#pragma unroll
                for (int nh = 0; nh < 2; ++nh)
                    nxt[8 + 2 * h + nh] =
                        *(const bf16x8*)(mp + (size_t)(16 * nh + col) * SEQ
                                         + en + 32 * h + g * 8);

            // QK^T (hi/lo split, C-init = -max)
            f32x4 S[2][4];
#pragma unroll
            for (int cc = 0; cc < 4; ++cc) {
#pragma unroll
                for (int s = 0; s < 2; ++s) {
                    f32x4 tac = __builtin_amdgcn_mfma_f32_16x16x32_bf16(ah[s], cur[4 + cc], minit[s], 0, 0, 0);
                    tac = __builtin_amdgcn_mfma_f32_16x16x32_bf16(al[s], cur[cc], tac, 0, 0, 0);
                    S[s][cc] = __builtin_amdgcn_mfma_f32_16x16x32_bf16(ah[s], cur[cc], tac, 0, 0, 0);
                }
            }
            // P = exp2(S), per-lane l partials, P -> LDS (bf16)
#pragma unroll
            for (int s = 0; s < 2; ++s) {
#pragma unroll
                for (int r = 0; r < 4; ++r) {
                    float p0 = __builtin_amdgcn_exp2f(S[s][0][r]);
                    float p1 = __builtin_amdgcn_exp2f(S[s][1][r]);
                    float p2 = __builtin_amdgcn_exp2f(S[s][2][r]);
                    float p3 = __builtin_amdgcn_exp2f(S[s][3][r]);
                    lsum[s][r] += (p0 + p1) + (p2 + p3);
                    unsigned w0 = (unsigned)f2bf(p0) | ((unsigned)f2bf(p1) << 16);
                    unsigned w1 = (unsigned)f2bf(p2) | ((unsigned)f2bf(p3) << 16);
                    unsigned* dst = (unsigned*)&Plds[wid][16 * s + 4 * g + r][col * 4];
                    dst[0] = w0;
                    dst[1] = w1;
                }
            }
            asm volatile("s_waitcnt lgkmcnt(0)" ::: "memory");
            __builtin_amdgcn_sched_barrier(0);
            // O += P * M  (bv from cur registers)
#pragma unroll
            for (int h = 0; h < 2; ++h) {
                bf16x8 pa[2];
#pragma unroll
                for (int s = 0; s < 2; ++s)
                    pa[s] = *(const bf16x8*)&Plds[wid][16 * s + col][32 * h + g * 8];
                O[0][0] = __builtin_amdgcn_mfma_f32_16x16x32_bf16(pa[0], cur[8 + 2 * h + 0], O[0][0], 0, 0, 0);
                O[0][1] = __builtin_amdgcn_mfma_f32_16x16x32_bf16(pa[0], cur[8 + 2 * h + 1], O[0][1], 0, 0, 0);
                O[1][0] = __builtin_amdgcn_mfma_f32_16x16x32_bf16(pa[1], cur[8 + 2 * h + 0], O[1][0], 0, 0, 0);
                O[1][1] = __builtin_amdgcn_mfma_f32_16x16x32_bf16(pa[1], cur[8 + 2 * h + 1], O[1][1], 0, 0, 0);
            }
            // keep program order: this iter's Plds reads before next iter's writes
            asm volatile("" ::: "memory");
        };
        for (int e0 = 0; e0 < SEQ; e0 += 128) {
            flash(tA, tB, e0);
            flash(tB, tA, e0 + 64);
        }
    }

    // ---- final l reduce across the 16 col-lanes
#pragma unroll
    for (int s = 0; s < 2; ++s)
#pragma unroll
        for (int r = 0; r < 4; ++r) {
            float l = lsum[s][r];
            l += __shfl_xor(l, 1);
            l += __shfl_xor(l, 2);
            l += __shfl_xor(l, 4);
            l += __shfl_xor(l, 8);
            lsum[s][r] = l;
        }

    // ---- epilogue: outb[b][d][n2*4+a] = O/l (bf16) — r5-exact
    const int bb = pair >> 2;
    const int aa = pair & 3;
#pragma unroll
    for (int s = 0; s < 2; ++s) {
#pragma unroll
        for (int r = 0; r < 4; ++r) {
            int d = d0 + 16 * s + 4 * g + r;
            float inv = 1.0f / lsum[s][r];
#pragma unroll
            for (int nh = 0; nh < 2; ++nh) {
                int n2 = 16 * nh + col;
                outb[((size_t)(bb * SEQ + d)) * 128 + n2 * 4 + aa] =
                    f2bf(O[s][nh][r] * inv);
            }
        }
    }
}

// ---------------------------------------------------------------------------
// Kernel 3: y = opre(bf16) @ w_out + b_out  (fp32 vector GEMM) — r5-exact
// ---------------------------------------------------------------------------
__global__ __launch_bounds__(256) void out_kernel(const unsigned short* __restrict__ opre,
                                                  const float* __restrict__ wout,
                                                  const float* __restrict__ bout,
                                                  float* __restrict__ y) {
    __shared__ __align__(16) float xs[8][128];
    const int r0 = blockIdx.x * 8;
    const int t  = threadIdx.x;
    {
        const unsigned* src = (const unsigned*)(opre + (size_t)r0 * 128);
        unsigned v0 = src[t * 2], v1 = src[t * 2 + 1];
        float* dst = &xs[0][0] + t * 4;
        dst[0] = bf2f((unsigned short)(v0 & 0xffff));
        dst[1] = bf2f((unsigned short)(v0 >> 16));
        dst[2] = bf2f((unsigned short)(v1 & 0xffff));
        dst[3] = bf2f((unsigned short)(v1 >> 16));
    }
    __syncthreads();

    const int c  = t & 127;
    const int rh = (t >> 7) * 4;
    float acc[4] = {0.f, 0.f, 0.f, 0.f};

    for (int i = 0; i < 128; i += 4) {
        float w0 = wout[(i + 0) * 128 + c];
        float w1 = wout[(i + 1) * 128 + c];
        float w2 = wout[(i + 2) * 128 + c];
        float w3 = wout[(i + 3) * 128 + c];
#pragma unroll
        for (int p = 0; p < 4; ++p) {
            float4 xp = *(const float4*)&xs[rh + p][i];
            acc[p] = fmaf(xp.x, w0, acc[p]);
            acc[p] = fmaf(xp.y, w1, acc[p]);
            acc[p] = fmaf(xp.z, w2, acc[p]);
            acc[p] = fmaf(xp.w, w3, acc[p]);
        }
    }
    float bb = bout[c];
#pragma unroll
    for (int p = 0; p < 4; ++p) {
        y[((size_t)(r0 + rh + p)) * 128 + c] = acc[p] + bb;
    }
}

// ---------------------------------------------------------------------------
extern "C" void kernel_launch(void* const* d_in, const int* in_sizes, int n_in,
                              void* d_out, int out_size, void* d_ws, size_t ws_size,
                              hipStream_t stream) {
    const float* x    = (const float*)d_in[0];
    const float* wqkv = (const float*)d_in[1];
    const float* wout = (const float*)d_in[2];
    const float* bout = (const float*)d_in[3];
    float* y = (float*)d_out;

    unsigned short* Qhi = (unsigned short*)d_ws;
    unsigned short* Qlo = Qhi + (size_t)16 * PAIR_ELEMS;
    unsigned short* Mhi = Qlo + (size_t)16 * PAIR_ELEMS;
    unsigned short* Mlo = Mhi + (size_t)16 * PAIR_ELEMS;
    unsigned short* Mpv = Mlo + (size_t)16 * PAIR_ELEMS;
    unsigned short* outb = Mpv + (size_t)16 * PAIR_ELEMS;

    kv_kernel<<<512, 256, 0, stream>>>(x, wqkv, Qhi, Qlo, Mhi, Mlo, Mpv);
    attn_kernel<<<512, 256, 0, stream>>>(Qhi, Qlo, Mhi, Mlo, Mpv, outb);
    out_kernel<<<2048, 256, 0, stream>>>(outb, wout, bout, y);
}